// Round 1
// baseline (405.036 us; speedup 1.0000x reference)
//
#include <hip/hip_runtime.h>
#include <hip/hip_bf16.h>
#include <cstdint>

#define NE 128     // n_e (K dim)
#define RR 256     // RANK*RANK (N dim)
#define MT 32      // batch rows per block

// LDS plan (bytes):
//   phase A (GEMM): occS[32][132] = 16896  |  Wt[16][260] = 16640   (total 33536)
//   phase B (LU):   jbuf[32*256]  = 32768  (aliases phase-A region)
#define SMEM_BYTES ((MT*132 + 16*260) * 4)

__global__ __launch_bounds__(256)
void jastrow_fused(const float* __restrict__ occ,
                   const float* __restrict__ Wg,
                   const float* __restrict__ bias,
                   float* __restrict__ out,
                   int B) {
  __shared__ __align__(16) char smem[SMEM_BYTES];
  float (*occS)[132] = (float (*)[132])smem;
  float (*Wt)[260]   = (float (*)[260])(smem + MT * 132 * 4);
  float* jbuf        = (float*)smem;

  const int tid = threadIdx.x;
  const long long b0 = (long long)blockIdx.x * MT;

  // ---- stage occ tile (32 rows x 128), fully coalesced float4 ----
  {
    const float* src = occ + b0 * NE;
    #pragma unroll
    for (int k = 0; k < 4; k++) {
      int flat = (tid + k * 256) * 4;       // 0..4095
      int row  = flat >> 7;                 // 0..31
      int e    = flat & 127;
      float4 v = *(const float4*)(src + flat);
      *(float4*)&occS[row][e] = v;
    }
  }

  // ---- accumulators init with bias ----
  const int rb = tid >> 5;   // 0..7  (4 batch rows each)
  const int cb = tid & 31;   // 0..31 (8 output cols each)
  float acc[4][8];
  {
    float4 bv0 = *(const float4*)(bias + cb * 8);
    float4 bv1 = *(const float4*)(bias + cb * 8 + 4);
    #pragma unroll
    for (int m = 0; m < 4; m++) {
      acc[m][0] = bv0.x; acc[m][1] = bv0.y; acc[m][2] = bv0.z; acc[m][3] = bv0.w;
      acc[m][4] = bv1.x; acc[m][5] = bv1.y; acc[m][6] = bv1.z; acc[m][7] = bv1.w;
    }
  }

  // W-tile read swizzle: logical 4-float chunk g -> physical g ^ ((g>>3)&1)
  const int s   = (cb >> 2) & 1;
  const int wi0 = ((cb * 2)     ^ s) * 4;   // word offset of logical cols cb*8..+3
  const int wi1 = ((cb * 2 + 1) ^ s) * 4;   // word offset of logical cols cb*8+4..+7

  // ---- GEMM: j[32][256] = occ_tile @ W, K-tiled by 16 ----
  for (int kt = 0; kt < 8; kt++) {
    __syncthreads();  // occS ready (iter 0) / previous-tile Wt reads done
    #pragma unroll
    for (int it = 0; it < 4; it++) {
      int flat = (tid + it * 256) * 4;      // 0..4095 over 16x256 tile
      int e    = flat >> 8;                 // 0..15
      int col  = flat & 255;
      float4 wv = *(const float4*)(Wg + (long long)(kt * 16 + e) * RR + col);
      int g  = col >> 2;
      int pg = g ^ ((g >> 3) & 1);
      *(float4*)&Wt[e][pg * 4] = wv;
    }
    __syncthreads();
    #pragma unroll
    for (int e4 = 0; e4 < 4; e4++) {
      float a[4][4];
      #pragma unroll
      for (int m = 0; m < 4; m++)
        *(float4*)a[m] = *(const float4*)&occS[rb * 4 + m][kt * 16 + e4 * 4];
      #pragma unroll
      for (int ee = 0; ee < 4; ee++) {
        float4 w0 = *(const float4*)&Wt[e4 * 4 + ee][wi0];
        float4 w1 = *(const float4*)&Wt[e4 * 4 + ee][wi1];
        float wv[8] = {w0.x, w0.y, w0.z, w0.w, w1.x, w1.y, w1.z, w1.w};
        #pragma unroll
        for (int m = 0; m < 4; m++) {
          #pragma unroll
          for (int c = 0; c < 8; c++)
            acc[m][c] = fmaf(a[m][ee], wv[c], acc[m][c]);
        }
      }
    }
  }

  __syncthreads();  // all occS/Wt reads done; safe to overwrite with jbuf

  // ---- scatter acc -> jbuf, swizzle: phys_word = w ^ (((w>>4)&7)<<2) ----
  {
    const int k4s = ((cb >> 1) & 7) << 2;
    #pragma unroll
    for (int m = 0; m < 4; m++) {
      int row = rb * 4 + m;
      float4 v0 = make_float4(acc[m][0], acc[m][1], acc[m][2], acc[m][3]);
      float4 v1 = make_float4(acc[m][4], acc[m][5], acc[m][6], acc[m][7]);
      *(float4*)&jbuf[row * 256 + ((cb * 8)     ^ k4s)] = v0;
      *(float4*)&jbuf[row * 256 + ((cb * 8 + 4) ^ k4s)] = v1;
    }
  }
  __syncthreads();

  // ---- wave-parallel LU with partial pivoting: 16 lanes = 16 rows ----
  const int r   = tid & 15;
  const int grp = tid >> 4;   // 0..15 (4 groups per wave)
  #pragma unroll
  for (int mi = 0; mi < 2; mi++) {
    const int jb = grp * 2 + mi;
    float x[16];
    #pragma unroll
    for (int i = 0; i < 4; i++) {
      int w  = r * 16 + i * 4;
      int pw = w ^ ((r & 7) << 2);
      float4 v = *(const float4*)&jbuf[jb * 256 + pw];
      x[i * 4 + 0] = v.x; x[i * 4 + 1] = v.y;
      x[i * 4 + 2] = v.z; x[i * 4 + 3] = v.w;
    }
    // A = I + j
    #pragma unroll
    for (int c = 0; c < 16; c++) x[c] += (c == r) ? 1.0f : 0.0f;

    unsigned used = 0u;
    int par = 0, zero = 0;
    float sumlog = 0.0f;
    #pragma unroll
    for (int k = 0; k < 16; k++) {
      float val = x[k];
      bool act  = ((used >> r) & 1u) == 0u;
      float key = act ? fabsf(val) : -1.0f;
      int   idx = r;
      #pragma unroll
      for (int d = 1; d < 16; d <<= 1) {
        float ko = __shfl_xor(key, d, 16);
        int   io = __shfl_xor(idx, d, 16);
        if (ko > key || (ko == key && io < idx)) { key = ko; idx = io; }
      }
      const int p = idx;                      // pivot row (same in all 16 lanes)
      float piv = __shfl(val, p, 16);
      sumlog += __log2f(fabsf(piv));
      par ^= (piv < 0.0f) ? 1 : 0;
      zero |= (piv == 0.0f) ? 1 : 0;
      par ^= __popc(used & (0xFFFFFFFFu << (p + 1))) & 1;   // inversion parity
      used |= 1u << p;
      float rp = (piv != 0.0f) ? (1.0f / piv) : 0.0f;
      float f  = (act && r != p) ? (val * rp) : 0.0f;       // frozen rows: f=0
      #pragma unroll
      for (int j = k + 1; j < 16; j++) {
        float t = __shfl(x[j], p, 16);
        x[j] = fmaf(-f, t, x[j]);
      }
    }
    if (r == 0) {
      float la = sumlog * 0.6931471805599453f;   // log2 -> ln
      float sg = zero ? 0.0f : (par ? -1.0f : 1.0f);
      long long b = b0 + jb;
      out[b] = sg;
      out[(long long)B + b] = la;
    }
  }
}

extern "C" void kernel_launch(void* const* d_in, const int* in_sizes, int n_in,
                              void* d_out, int out_size, void* d_ws, size_t ws_size,
                              hipStream_t stream) {
  const float* occ  = (const float*)d_in[0];
  const float* Wg   = (const float*)d_in[1];
  const float* bias = (const float*)d_in[2];
  float* out = (float*)d_out;
  const int B = in_sizes[0] / NE;        // 262144
  const int nblk = B / MT;               // 8192
  hipLaunchKernelGGL(jastrow_fused, dim3(nblk), dim3(256), 0, stream,
                     occ, Wg, bias, out, B);
}

// Round 3
// 344.324 us; speedup vs baseline: 1.1763x; 1.1763x over previous
//
#include <hip/hip_runtime.h>
#include <cstdint>

typedef __attribute__((ext_vector_type(8))) short short8;
typedef __attribute__((ext_vector_type(4))) float f32x4;

#define NE 128     // n_e (K)
#define RR 256     // RANK*RANK (N)
#define MT 64      // batch rows per block
#define JST 260    // jbuf row stride (words)

__device__ __forceinline__ unsigned short f2bf(float x) {
  unsigned u = __builtin_bit_cast(unsigned, x);
  unsigned r = (u + 0x7FFFu + ((u >> 16) & 1u)) >> 16;
  return (unsigned short)r;
}
__device__ __forceinline__ float bf2f(unsigned short h) {
  unsigned u = ((unsigned)h) << 16;
  return __builtin_bit_cast(float, u);
}

// ---- pre-kernel: 3-way split W (f32 [128][256]) -> h/m/l bf16, fragment-major
// slot: elem e = ((kt*16 + ct)*64 + lane)*8 + u
//   with k = kt*32 + (lane>>4)*8 + u, col = ct*16 + (lane&15)
__global__ __launch_bounds__(256)
void wsplit3_kernel(const float* __restrict__ W,
                    unsigned short* __restrict__ wh,
                    unsigned short* __restrict__ wm,
                    unsigned short* __restrict__ wl) {
  int t = blockIdx.x * 256 + threadIdx.x;   // 0..32767
  int k = t >> 8, col = t & 255;
  float w = W[t];
  unsigned short h1 = f2bf(w);
  float r1 = w - bf2f(h1);
  unsigned short h2 = f2bf(r1);
  float r2 = r1 - bf2f(h2);
  unsigned short h3 = f2bf(r2);
  int kt = k >> 5, klo = k & 31;
  int lane = ((klo >> 3) << 4) | (col & 15);
  int u = klo & 7;
  int ct = col >> 4;
  int e = ((kt * 16 + ct) * 64 + lane) * 8 + u;
  wh[e] = h1; wm[e] = h2; wl[e] = h3;
}

// ---- main fused kernel ----
__global__ __launch_bounds__(256, 2)
void jastrow_mfma(const float* __restrict__ occ,
                  const unsigned short* __restrict__ wh,
                  const unsigned short* __restrict__ wm,
                  const unsigned short* __restrict__ wl,
                  const float* __restrict__ bias,
                  float* __restrict__ out, int B) {
  // phase A: occS f32 [64][132] (33792 B); phase B: jbuf f32 [64][260] (66560 B)
  __shared__ __align__(16) char smem[MT * JST * 4];
  float* occS = (float*)smem;
  float* jbuf = (float*)smem;

  const int tid  = threadIdx.x;
  const int lane = tid & 63;
  const int wv   = tid >> 6;        // wave 0..3
  const int wr   = wv >> 1;         // row half (32 rows)
  const int wc   = wv & 1;          // col half (128 cols)
  const int l15  = lane & 15;
  const int lh   = lane >> 4;
  const long long b0 = (long long)blockIdx.x * MT;

  // ---- stage occ tile 64x128 f32 -> LDS [64][132] ----
  {
    const float* src = occ + b0 * NE;
    #pragma unroll
    for (int p = 0; p < 8; p++) {
      int flat = (tid + p * 256) * 4;
      int row = flat >> 7, e = flat & 127;
      f32x4 v = *(const f32x4*)(src + flat);
      *(f32x4*)(occS + row * 132 + e) = v;
    }
  }
  __syncthreads();

  // ---- A fragments: 3-way bf16 split into registers ----
  short8 Ah[2][4], Am[2][4], Al[2][4];
  #pragma unroll
  for (int rt = 0; rt < 2; rt++) {
    #pragma unroll
    for (int kt = 0; kt < 4; kt++) {
      const float* p = occS + (wr * 32 + rt * 16 + l15) * 132 + kt * 32 + lh * 8;
      f32x4 v0 = *(const f32x4*)p;
      f32x4 v1 = *(const f32x4*)(p + 4);
      float xs[8] = {v0[0], v0[1], v0[2], v0[3], v1[0], v1[1], v1[2], v1[3]};
      #pragma unroll
      for (int u = 0; u < 8; u++) {
        unsigned short h1 = f2bf(xs[u]);
        float r1 = xs[u] - bf2f(h1);
        unsigned short h2 = f2bf(r1);
        float r2 = r1 - bf2f(h2);
        Ah[rt][kt][u] = (short)h1;
        Am[rt][kt][u] = (short)h2;
        Al[rt][kt][u] = (short)f2bf(r2);
      }
    }
  }
  __syncthreads();   // all occS reads done; jbuf may be written after this

  // ---- GEMM: 6-MFMA triple-split (err ~2^-27 rel, below fp32-LU noise) ----
  f32x4 acc[2][8];
  #pragma unroll
  for (int ct = 0; ct < 8; ct++) {
    float bv = bias[(wc * 8 + ct) * 16 + l15];
    f32x4 a; a[0] = bv; a[1] = bv; a[2] = bv; a[3] = bv;
    acc[0][ct] = a; acc[1][ct] = a;
  }
  #pragma unroll
  for (int kt = 0; kt < 4; kt++) {
    #pragma unroll
    for (int ct = 0; ct < 8; ct++) {
      const int ctg = wc * 8 + ct;
      int fo = ((kt * 16 + ctg) * 64 + lane) * 8;
      short8 bh = *(const short8*)(wh + fo);
      short8 bm = *(const short8*)(wm + fo);
      short8 bl = *(const short8*)(wl + fo);
      #pragma unroll
      for (int rt = 0; rt < 2; rt++) {
        f32x4 c = acc[rt][ct];
        c = __builtin_amdgcn_mfma_f32_16x16x32_bf16(Ah[rt][kt], bh, c, 0, 0, 0);
        c = __builtin_amdgcn_mfma_f32_16x16x32_bf16(Ah[rt][kt], bm, c, 0, 0, 0);
        c = __builtin_amdgcn_mfma_f32_16x16x32_bf16(Am[rt][kt], bh, c, 0, 0, 0);
        c = __builtin_amdgcn_mfma_f32_16x16x32_bf16(Am[rt][kt], bm, c, 0, 0, 0);
        c = __builtin_amdgcn_mfma_f32_16x16x32_bf16(Ah[rt][kt], bl, c, 0, 0, 0);
        c = __builtin_amdgcn_mfma_f32_16x16x32_bf16(Al[rt][kt], bh, c, 0, 0, 0);
        acc[rt][ct] = c;
      }
    }
  }

  // ---- write j to jbuf (plain layout, padded stride kills write conflicts) ----
  #pragma unroll
  for (int ct = 0; ct < 8; ct++) {
    const int ctg = wc * 8 + ct;
    #pragma unroll
    for (int rt = 0; rt < 2; rt++) {
      #pragma unroll
      for (int i = 0; i < 4; i++) {
        int m = wr * 32 + rt * 16 + lh * 4 + i;
        jbuf[m * JST + ctg * 16 + l15] = acc[rt][ct][i];
      }
    }
  }
  __syncthreads();

  // ---- wave-parallel LU with partial pivoting (R1-verbatim argmax) ----
  const int r   = tid & 15;
  const int grp = tid >> 4;        // 0..15, each does 4 matrices
  #pragma unroll 1
  for (int mi = 0; mi < 4; mi++) {
    const int jb = grp * 4 + mi;
    float x[16];
    #pragma unroll
    for (int i = 0; i < 4; i++) {
      f32x4 v = *(const f32x4*)&jbuf[jb * JST + r * 16 + i * 4];
      x[i * 4 + 0] = v[0]; x[i * 4 + 1] = v[1];
      x[i * 4 + 2] = v[2]; x[i * 4 + 3] = v[3];
    }
    #pragma unroll
    for (int c = 0; c < 16; c++) x[c] += (c == r) ? 1.0f : 0.0f;

    unsigned used = 0u;
    int par = 0, zero = 0;
    float sumlog = 0.0f;
    #pragma unroll
    for (int k = 0; k < 16; k++) {
      float val = x[k];
      bool act  = ((used >> r) & 1u) == 0u;
      float key = act ? fabsf(val) : -1.0f;
      int   idx = r;
      #pragma unroll
      for (int d = 1; d < 16; d <<= 1) {
        float ko = __shfl_xor(key, d, 16);
        int   io = __shfl_xor(idx, d, 16);
        if (ko > key || (ko == key && io < idx)) { key = ko; idx = io; }
      }
      const int p = idx;
      float piv = __shfl(val, p, 16);
      sumlog += __log2f(fabsf(piv));
      par ^= (piv < 0.0f) ? 1 : 0;
      zero |= (piv == 0.0f) ? 1 : 0;
      par ^= __popc(used & (0xFFFFFFFFu << (p + 1))) & 1;   // inversion parity
      used |= 1u << p;
      float rp = (piv != 0.0f) ? (1.0f / piv) : 0.0f;
      float f  = (act && r != p) ? (val * rp) : 0.0f;
      #pragma unroll
      for (int j = k + 1; j < 16; j++) {
        float t = __shfl(x[j], p, 16);
        x[j] = fmaf(-f, t, x[j]);
      }
    }
    if (r == 0) {
      float la = sumlog * 0.6931471805599453f;
      float sg = zero ? 0.0f : (par ? -1.0f : 1.0f);
      long long b = b0 + jb;
      out[b] = sg;
      out[(long long)B + b] = la;
    }
  }
}

extern "C" void kernel_launch(void* const* d_in, const int* in_sizes, int n_in,
                              void* d_out, int out_size, void* d_ws, size_t ws_size,
                              hipStream_t stream) {
  const float* occ  = (const float*)d_in[0];
  const float* Wg   = (const float*)d_in[1];
  const float* bias = (const float*)d_in[2];
  float* out = (float*)d_out;
  const int B = in_sizes[0] / NE;          // 262144
  unsigned short* wh = (unsigned short*)d_ws;
  unsigned short* wm = wh + NE * RR;       // 32768 elems each
  unsigned short* wl = wm + NE * RR;       // 196608 B total in d_ws

  hipLaunchKernelGGL(wsplit3_kernel, dim3(NE * RR / 256), dim3(256), 0, stream,
                     Wg, wh, wm, wl);
  hipLaunchKernelGGL(jastrow_mfma, dim3(B / MT), dim3(256), 0, stream,
                     occ, wh, wm, wl, bias, out, B);
}

// Round 4
// 178.377 us; speedup vs baseline: 2.2707x; 1.9303x over previous
//
#include <hip/hip_runtime.h>
#include <cstdint>

typedef __attribute__((ext_vector_type(8))) short short8;
typedef __attribute__((ext_vector_type(4))) float f32x4;

#define NE 128     // n_e (K)
#define RR 256     // RANK*RANK (N)
#define MT 64      // batch rows per block
#define JST 260    // jbuf per-matrix stride (words)

__device__ __forceinline__ unsigned short f2bf(float x) {
  unsigned u = __builtin_bit_cast(unsigned, x);
  unsigned r = (u + 0x7FFFu + ((u >> 16) & 1u)) >> 16;
  return (unsigned short)r;
}
__device__ __forceinline__ float bf2f(unsigned short h) {
  unsigned u = ((unsigned)h) << 16;
  return __builtin_bit_cast(float, u);
}
__device__ __forceinline__ float bperm_f(int byteidx, float v) {
  return __builtin_bit_cast(float,
      __builtin_amdgcn_ds_bpermute(byteidx, __builtin_bit_cast(int, v)));
}
template<int CTRL>
__device__ __forceinline__ unsigned dpp_max8(unsigned k) {
  unsigned o = (unsigned)__builtin_amdgcn_update_dpp(0, (int)k, CTRL, 0xF, 0xF, true);
  return o > k ? o : k;
}

// ---- pre-kernel: 3-way split W (f32 [128][256]) -> h/m/l bf16, fragment-major
__global__ __launch_bounds__(256)
void wsplit3_kernel(const float* __restrict__ W,
                    unsigned short* __restrict__ wh,
                    unsigned short* __restrict__ wm,
                    unsigned short* __restrict__ wl) {
  int t = blockIdx.x * 256 + threadIdx.x;   // 0..32767
  int k = t >> 8, col = t & 255;
  float w = W[t];
  unsigned short h1 = f2bf(w);
  float r1 = w - bf2f(h1);
  unsigned short h2 = f2bf(r1);
  float r2 = r1 - bf2f(h2);
  unsigned short h3 = f2bf(r2);
  int kt = k >> 5, klo = k & 31;
  int lane = ((klo >> 3) << 4) | (col & 15);
  int u = klo & 7;
  int ct = col >> 4;
  int e = ((kt * 16 + ct) * 64 + lane) * 8 + u;
  wh[e] = h1; wm[e] = h2; wl[e] = h3;
}

// ---- main fused kernel ----
__global__ __launch_bounds__(256, 2)
void jastrow_mfma(const float* __restrict__ occ,
                  const unsigned short* __restrict__ wh,
                  const unsigned short* __restrict__ wm,
                  const unsigned short* __restrict__ wl,
                  const float* __restrict__ bias,
                  float* __restrict__ out, int B) {
  // phase A: occS f32 [64][132] = 33792 B; per-phase jbuf f32 [32][260] = 33280 B (aliased)
  __shared__ __align__(16) char smem[64 * 132 * 4];
  float* occS = (float*)smem;
  float* jbuf = (float*)smem;

  const int tid  = threadIdx.x;
  const int lane = tid & 63;
  const int wv   = tid >> 6;        // wave 0..3
  const int wr   = wv >> 1;         // row half (32 rows)
  const int wc   = wv & 1;          // col half (128 cols)
  const int l15  = lane & 15;
  const int lh   = lane >> 4;
  const long long b0 = (long long)blockIdx.x * MT;

  // ---- stage occ tile 64x128 f32 -> LDS [64][132] ----
  {
    const float* src = occ + b0 * NE;
    #pragma unroll
    for (int p = 0; p < 8; p++) {
      int flat = (tid + p * 256) * 4;
      int row = flat >> 7, e = flat & 127;
      f32x4 v = *(const f32x4*)(src + flat);
      *(f32x4*)(occS + row * 132 + e) = v;
    }
  }
  __syncthreads();

  // ---- A fragments: 3-way bf16 split into registers ----
  short8 Ah[2][4], Am[2][4], Al[2][4];
  #pragma unroll
  for (int rt = 0; rt < 2; rt++) {
    #pragma unroll
    for (int kt = 0; kt < 4; kt++) {
      const float* p = occS + (wr * 32 + rt * 16 + l15) * 132 + kt * 32 + lh * 8;
      f32x4 v0 = *(const f32x4*)p;
      f32x4 v1 = *(const f32x4*)(p + 4);
      float xs[8] = {v0[0], v0[1], v0[2], v0[3], v1[0], v1[1], v1[2], v1[3]};
      #pragma unroll
      for (int u = 0; u < 8; u++) {
        unsigned short h1 = f2bf(xs[u]);
        float r1 = xs[u] - bf2f(h1);
        unsigned short h2 = f2bf(r1);
        float r2 = r1 - bf2f(h2);
        Ah[rt][kt][u] = (short)h1;
        Am[rt][kt][u] = (short)h2;
        Al[rt][kt][u] = (short)f2bf(r2);
      }
    }
  }
  __syncthreads();   // all occS reads done; jbuf may be written after this

  // ---- GEMM: 6-MFMA triple-split ----
  f32x4 acc[2][8];
  #pragma unroll
  for (int ct = 0; ct < 8; ct++) {
    float bv = bias[(wc * 8 + ct) * 16 + l15];
    f32x4 a; a[0] = bv; a[1] = bv; a[2] = bv; a[3] = bv;
    acc[0][ct] = a; acc[1][ct] = a;
  }
  #pragma unroll
  for (int kt = 0; kt < 4; kt++) {
    #pragma unroll
    for (int ct = 0; ct < 8; ct++) {
      const int ctg = wc * 8 + ct;
      int fo = ((kt * 16 + ctg) * 64 + lane) * 8;
      short8 bh = *(const short8*)(wh + fo);
      short8 bm = *(const short8*)(wm + fo);
      short8 bl = *(const short8*)(wl + fo);
      #pragma unroll
      for (int rt = 0; rt < 2; rt++) {
        f32x4 c = acc[rt][ct];
        c = __builtin_amdgcn_mfma_f32_16x16x32_bf16(Ah[rt][kt], bh, c, 0, 0, 0);
        c = __builtin_amdgcn_mfma_f32_16x16x32_bf16(Ah[rt][kt], bm, c, 0, 0, 0);
        c = __builtin_amdgcn_mfma_f32_16x16x32_bf16(Am[rt][kt], bh, c, 0, 0, 0);
        c = __builtin_amdgcn_mfma_f32_16x16x32_bf16(Am[rt][kt], bm, c, 0, 0, 0);
        c = __builtin_amdgcn_mfma_f32_16x16x32_bf16(Ah[rt][kt], bl, c, 0, 0, 0);
        c = __builtin_amdgcn_mfma_f32_16x16x32_bf16(Al[rt][kt], bh, c, 0, 0, 0);
        acc[rt][ct] = c;
      }
    }
  }

  // ---- two phases: write 32 matrices to jbuf, 8-lane-per-matrix LU ----
  const int l8  = tid & 7;          // lane within matrix group (rows l8, l8+8)
  const int g   = tid >> 3;         // matrix 0..31 within phase
  const int gb4 = (lane & 0x38) << 2;  // wave-local group base, byte index

  for (int ph = 0; ph < 2; ph++) {
    if (wr == ph) {
      #pragma unroll
      for (int ct = 0; ct < 8; ct++) {
        const int ctg = wc * 8 + ct;
        #pragma unroll
        for (int rt = 0; rt < 2; rt++) {
          #pragma unroll
          for (int i = 0; i < 4; i++) {
            int mloc = rt * 16 + lh * 4 + i;
            jbuf[mloc * JST + ctg * 16 + l15] = acc[rt][ct][i];
          }
        }
      }
    }
    __syncthreads();

    float xlo[16], xhi[16];
    #pragma unroll
    for (int c4 = 0; c4 < 4; c4++) {
      f32x4 v = *(const f32x4*)&jbuf[g * JST + l8 * 16 + c4 * 4];
      f32x4 w = *(const f32x4*)&jbuf[g * JST + (l8 + 8) * 16 + c4 * 4];
      xlo[c4*4+0] = v[0]; xlo[c4*4+1] = v[1]; xlo[c4*4+2] = v[2]; xlo[c4*4+3] = v[3];
      xhi[c4*4+0] = w[0]; xhi[c4*4+1] = w[1]; xhi[c4*4+2] = w[2]; xhi[c4*4+3] = w[3];
    }
    #pragma unroll
    for (int c = 0; c < 16; c++) {
      xlo[c] += (c == l8)     ? 1.0f : 0.0f;
      xhi[c] += (c == l8 + 8) ? 1.0f : 0.0f;
    }

    unsigned used = 0u;
    int par = 0, esum = 0;
    float prodm = 1.0f;
    #pragma unroll
    for (int k = 0; k < 16; k++) {
      float vlo = xlo[k], vhi = xhi[k];
      bool actlo = ((used >> l8) & 1u) == 0u;
      bool acthi = ((used >> (l8 + 8)) & 1u) == 0u;
      unsigned klo_ = actlo ? ((__builtin_bit_cast(unsigned, fabsf(vlo)) & 0xFFFFFFE0u)
                               | 0x10u | (unsigned)(15 - l8)) : 0u;
      unsigned khi_ = acthi ? ((__builtin_bit_cast(unsigned, fabsf(vhi)) & 0xFFFFFFE0u)
                               | 0x10u | (unsigned)(7 - l8)) : 0u;
      unsigned key = klo_ > khi_ ? klo_ : khi_;
      key = dpp_max8<0x141>(key);   // row_half_mirror  (xor 7 within 8)
      key = dpp_max8<0x4E>(key);    // quad_perm [2,3,0,1] (xor 2)
      key = dpp_max8<0xB1>(key);    // quad_perm [1,0,3,2] (xor 1)
      int p = 15 - (int)(key & 0xFu);
      int bidx = gb4 | ((p & 7) << 2);
      bool ph8 = (p & 8) != 0;
      float selk = ph8 ? xhi[k] : xlo[k];
      float piv = bperm_f(bidx, selk);
      int e; float mant = frexpf(piv, &e);
      prodm *= mant; esum += e;
      par ^= __popc(used & (0xFFFFFFFFu << (p + 1))) & 1;   // inversion parity
      used |= 1u << p;
      float rp = (piv != 0.0f) ? (1.0f / piv) : 0.0f;
      float flo = (actlo && l8 != p)       ? vlo * rp : 0.0f;
      float fhi = (acthi && (l8 + 8) != p) ? vhi * rp : 0.0f;
      #pragma unroll
      for (int j = k + 1; j < 16; j++) {
        float sel = ph8 ? xhi[j] : xlo[j];
        float t = bperm_f(bidx, sel);
        xlo[j] = fmaf(-flo, t, xlo[j]);
        xhi[j] = fmaf(-fhi, t, xhi[j]);
      }
    }
    if (l8 == 0) {
      float la = (__log2f(fabsf(prodm)) + (float)esum) * 0.6931471805599453f;
      int neg = (prodm < 0.0f) ? 1 : 0;
      float sg = (prodm == 0.0f) ? 0.0f : (((neg ^ par) != 0) ? -1.0f : 1.0f);
      long long b = b0 + ph * 32 + g;
      out[b] = sg;
      out[(long long)B + b] = la;
    }
    __syncthreads();
  }
}

extern "C" void kernel_launch(void* const* d_in, const int* in_sizes, int n_in,
                              void* d_out, int out_size, void* d_ws, size_t ws_size,
                              hipStream_t stream) {
  const float* occ  = (const float*)d_in[0];
  const float* Wg   = (const float*)d_in[1];
  const float* bias = (const float*)d_in[2];
  float* out = (float*)d_out;
  const int B = in_sizes[0] / NE;          // 262144
  unsigned short* wh = (unsigned short*)d_ws;
  unsigned short* wm = wh + NE * RR;
  unsigned short* wl = wm + NE * RR;       // 196608 B total in d_ws

  hipLaunchKernelGGL(wsplit3_kernel, dim3(NE * RR / 256), dim3(256), 0, stream,
                     Wg, wh, wm, wl);
  hipLaunchKernelGGL(jastrow_mfma, dim3(B / MT), dim3(256), 0, stream,
                     occ, wh, wm, wl, bias, out, B);
}